// Round 1
// baseline (194.277 us; speedup 1.0000x reference)
//
#include <hip/hip_runtime.h>
#include <math.h>

#define NB 2
#define NH 8
#define SS 160
#define DD 64
#define NC 16     // D/4 float4-chunks along h
#define NT 256

// LDS chunk addressing: buffer is [c(16)][s(160)] of float4.
// XOR-swizzle low 4 bits of s by c so that:
//  - staging stores (lanes vary c fast)   -> 2-way bank conflict (free)
//  - A-loads (4 distinct ty per wave)     -> conflict-free
//  - B-loads (16 distinct tx per wave)    -> 2-way (free)
__device__ __forceinline__ int chunk_idx(int c, int s) {
    return c * SS + ((s & ~15) | ((s ^ c) & 15));
}

__global__ __launch_bounds__(NT, 2) void tritt_kernel(
    const float* __restrict__ q,  const float* __restrict__ k1,
    const float* __restrict__ k2, const float* __restrict__ v1,
    const float* __restrict__ v2, float* __restrict__ out)
{
    __shared__ float smem[20480];              // 80 KB -> 2 blocks/CU
    float4* aq = (float4*)smem;                // k1 * q  (2560 chunks, 40 KB)
    float4* bq = (float4*)(smem + 10240);      // k2      (40 KB)

    const int tid = threadIdx.x;
    const int blk = blockIdx.x;
    const int bh  = blk / SS;                  // b*H + h
    const int qi  = blk % SS;
    const size_t base = (size_t)bh * SS * DD;

    const float4* qrow = (const float4*)(q  + base + (size_t)qi * DD); // 16 chunks
    const float4* k1g  = (const float4*)(k1 + base);
    const float4* k2g  = (const float4*)(k2 + base);

    // ---- stage k1*q and k2 into LDS (coalesced global float4 reads) ----
    #pragma unroll
    for (int it = 0; it < 10; ++it) {
        int f = tid + NT * it;                 // 0..2559
        int s = f >> 4, c = f & 15;
        float4 kv = k1g[f];
        float4 qv = qrow[c];
        float4 av;
        av.x = kv.x * qv.x; av.y = kv.y * qv.y;
        av.z = kv.z * qv.z; av.w = kv.w * qv.w;
        int ci = chunk_idx(c, s);
        aq[ci] = av;
        bq[ci] = k2g[f];
    }
    __syncthreads();

    // ---- 160x160 score tile: thread (tx,ty) owns s=ty+16i, t=tx+16j ----
    const int tx = tid & 15, ty = tid >> 4;
    float acc[10][10];
    #pragma unroll
    for (int i = 0; i < 10; ++i)
        #pragma unroll
        for (int j = 0; j < 10; ++j) acc[i][j] = 0.f;

    #pragma unroll 1
    for (int c = 0; c < NC; ++c) {
        float4 av[10];
        #pragma unroll
        for (int i = 0; i < 10; ++i) av[i] = aq[chunk_idx(c, ty + 16 * i)];
        #pragma unroll
        for (int j = 0; j < 10; ++j) {
            float4 bv = bq[chunk_idx(c, tx + 16 * j)];
            #pragma unroll
            for (int i = 0; i < 10; ++i) {
                acc[i][j] = fmaf(av[i].x, bv.x, acc[i][j]);
                acc[i][j] = fmaf(av[i].y, bv.y, acc[i][j]);
                acc[i][j] = fmaf(av[i].z, bv.z, acc[i][j]);
                acc[i][j] = fmaf(av[i].w, bv.w, acc[i][j]);
            }
        }
    }
    __syncthreads();   // staging buffers dead; alias phase-2 arrays below

    float* A1   = smem;                 // [160] row sums (over t)
    float* A2   = smem + SS;            // [160] col sums (over s)
    float* wred = smem + 2 * SS;        // [8]  per-wave max / sum
    float* zred = smem + 2 * SS + 8;    // [256] gemv partials

    const int lane = tid & 63;
    const int wid  = tid >> 6;

    // ---- block max ----
    float mloc = -1e30f;
    #pragma unroll
    for (int i = 0; i < 10; ++i)
        #pragma unroll
        for (int j = 0; j < 10; ++j) mloc = fmaxf(mloc, acc[i][j]);
    #pragma unroll
    for (int off = 32; off; off >>= 1) mloc = fmaxf(mloc, __shfl_xor(mloc, off, 64));
    if (lane == 0) wred[wid] = mloc;
    if (tid < SS)  A2[tid] = 0.f;
    __syncthreads();
    const float m = fmaxf(fmaxf(wred[0], wred[1]), fmaxf(wred[2], wred[3]));

    // ---- exp in place + block sum ----
    float lsum = 0.f;
    #pragma unroll
    for (int i = 0; i < 10; ++i)
        #pragma unroll
        for (int j = 0; j < 10; ++j) {
            float e = __expf(acc[i][j] - m);
            acc[i][j] = e;
            lsum += e;
        }
    #pragma unroll
    for (int off = 32; off; off >>= 1) lsum += __shfl_xor(lsum, off, 64);
    if (lane == 0) wred[4 + wid] = lsum;

    // ---- row sums -> A1 (reduce over the 16 tx lanes, same-wave) ----
    #pragma unroll
    for (int i = 0; i < 10; ++i) {
        float r = 0.f;
        #pragma unroll
        for (int j = 0; j < 10; ++j) r += acc[i][j];
        r += __shfl_xor(r, 1, 64); r += __shfl_xor(r, 2, 64);
        r += __shfl_xor(r, 4, 64); r += __shfl_xor(r, 8, 64);
        if (tx == 0) A1[ty + 16 * i] = r;       // unique writer per s
    }
    // ---- col sums -> A2 (4 in-wave ty via shfl, 4 waves via LDS atomic) ----
    #pragma unroll
    for (int j = 0; j < 10; ++j) {
        float cs = 0.f;
        #pragma unroll
        for (int i = 0; i < 10; ++i) cs += acc[i][j];
        cs += __shfl_xor(cs, 16, 64);
        cs += __shfl_xor(cs, 32, 64);
        if (lane < 16) atomicAdd(&A2[tx + 16 * j], cs);
    }
    __syncthreads();

    const float l = (wred[4] + wred[5]) + (wred[6] + wred[7]);
    if (tid == 0)
        out[(size_t)NB * NH * SS * DD + (size_t)bh * SS + qi] = m + __logf(l);

    // ---- z[q,d] = (A1 @ v1 + A2 @ v2) / l ----
    const int d    = tid & 63;
    const int part = tid >> 6;                  // 0..3, 40 rows each
    const float* v1p = v1 + base;
    const float* v2p = v2 + base;
    float z = 0.f;
    #pragma unroll 4
    for (int s = part * 40; s < part * 40 + 40; ++s)
        z = fmaf(A1[s], v1p[s * DD + d], fmaf(A2[s], v2p[s * DD + d], z));
    zred[tid] = z;
    __syncthreads();
    if (tid < DD) {
        float zz = (zred[tid] + zred[tid + 64]) + (zred[tid + 128] + zred[tid + 192]);
        out[((size_t)bh * SS + qi) * DD + tid] = zz / l;
    }
}

extern "C" void kernel_launch(void* const* d_in, const int* in_sizes, int n_in,
                              void* d_out, int out_size, void* d_ws, size_t ws_size,
                              hipStream_t stream) {
    const float* q  = (const float*)d_in[0];
    const float* k1 = (const float*)d_in[1];
    const float* k2 = (const float*)d_in[2];
    const float* v1 = (const float*)d_in[3];
    const float* v2 = (const float*)d_in[4];
    float* out = (float*)d_out;
    tritt_kernel<<<dim3(NB * NH * SS), dim3(NT), 0, stream>>>(q, k1, k2, v1, v2, out);
}

// Round 2
// 184.763 us; speedup vs baseline: 1.0515x; 1.0515x over previous
//
#include <hip/hip_runtime.h>
#include <math.h>

#define NB 2
#define NH 8
#define SS 160
#define DD 64
#define NC 16     // D/4 float4-chunks along h
#define NT 256

// LDS chunk layout: [c(16)][s(160)] of float4, with the low 4 bits of s
// XOR-swizzled by c. For fixed c this is base(c, low4) + 16*i  -> all score-
// loop ds_reads use immediate offsets (stride 256B), zero per-load VALU.
__device__ __forceinline__ int chunk_idx(int c, int s) {
    return c * SS + ((s & ~15) | ((s ^ c) & 15));
}

__global__ __launch_bounds__(NT, 1) void tritt_kernel(
    const float* __restrict__ q,  const float* __restrict__ k1,
    const float* __restrict__ k2, const float* __restrict__ v1,
    const float* __restrict__ v2, float* __restrict__ out)
{
    __shared__ float smem[20480];              // 80 KB -> 2 blocks/CU (LDS-capped)
    float4* aq = (float4*)smem;                // k1 * q  (2560 chunks, 40 KB)
    float4* bq = (float4*)(smem + 10240);      // k2      (40 KB)

    const int tid = threadIdx.x;
    const int blk = blockIdx.x;
    const int bh  = blk / SS;                  // b*H + h
    const int qi  = blk % SS;
    const size_t base = (size_t)bh * SS * DD;

    const float4* qrow = (const float4*)(q  + base + (size_t)qi * DD); // 16 chunks
    const float4* k1g  = (const float4*)(k1 + base);
    const float4* k2g  = (const float4*)(k2 + base);

    // ---- stage k1*q and k2 into LDS (coalesced global float4 reads) ----
    #pragma unroll
    for (int it = 0; it < 10; ++it) {
        int f = tid + NT * it;                 // 0..2559
        int s = f >> 4, c = f & 15;
        float4 kv = k1g[f];
        float4 qv = qrow[c];
        float4 av;
        av.x = kv.x * qv.x; av.y = kv.y * qv.y;
        av.z = kv.z * qv.z; av.w = kv.w * qv.w;
        int ci = chunk_idx(c, s);
        aq[ci] = av;
        bq[ci] = k2g[f];
    }
    __syncthreads();

    // ---- 160x160 score tile: thread (tx,ty) owns s=ty+16i, t=tx+16j ----
    const int tx = tid & 15, ty = tid >> 4;
    float acc[10][10];
    #pragma unroll
    for (int i = 0; i < 10; ++i)
        #pragma unroll
        for (int j = 0; j < 10; ++j) acc[i][j] = 0.f;

    #pragma unroll 1
    for (int c = 0; c < NC; ++c) {
        // row bases for this c: all subsequent reads are base + 16*idx (imm offs)
        const float4* __restrict__ arow = aq + c * SS + ((ty ^ c) & 15);
        const float4* __restrict__ brow = bq + c * SS + ((tx ^ c) & 15);
        float4 av[10];
        #pragma unroll
        for (int i = 0; i < 10; ++i) av[i] = arow[16 * i];
        #pragma unroll
        for (int j = 0; j < 10; ++j) {
            float4 bv = brow[16 * j];
            #pragma unroll
            for (int i = 0; i < 10; ++i) {
                acc[i][j] = fmaf(av[i].x, bv.x, acc[i][j]);
                acc[i][j] = fmaf(av[i].y, bv.y, acc[i][j]);
                acc[i][j] = fmaf(av[i].z, bv.z, acc[i][j]);
                acc[i][j] = fmaf(av[i].w, bv.w, acc[i][j]);
            }
        }
    }
    __syncthreads();   // staging buffers dead; alias phase-2 arrays below

    float* A1   = smem;                 // [160] row sums (over t)
    float* A2   = smem + SS;            // [160] col sums (over s)
    float* wred = smem + 2 * SS;        // [8]  per-wave max / sum
    float* zred = smem + 2 * SS + 8;    // [256] gemv partials

    const int lane = tid & 63;
    const int wid  = tid >> 6;

    // ---- block max ----
    float mloc = -1e30f;
    #pragma unroll
    for (int i = 0; i < 10; ++i)
        #pragma unroll
        for (int j = 0; j < 10; ++j) mloc = fmaxf(mloc, acc[i][j]);
    #pragma unroll
    for (int off = 32; off; off >>= 1) mloc = fmaxf(mloc, __shfl_xor(mloc, off, 64));
    if (lane == 0) wred[wid] = mloc;
    if (tid < SS)  A2[tid] = 0.f;
    __syncthreads();
    const float m = fmaxf(fmaxf(wred[0], wred[1]), fmaxf(wred[2], wred[3]));

    // ---- exp in place + block sum ----
    float lsum = 0.f;
    #pragma unroll
    for (int i = 0; i < 10; ++i)
        #pragma unroll
        for (int j = 0; j < 10; ++j) {
            float e = __expf(acc[i][j] - m);
            acc[i][j] = e;
            lsum += e;
        }
    #pragma unroll
    for (int off = 32; off; off >>= 1) lsum += __shfl_xor(lsum, off, 64);
    if (lane == 0) wred[4 + wid] = lsum;

    // ---- row sums -> A1 (reduce over the 16 tx lanes, same-wave) ----
    #pragma unroll
    for (int i = 0; i < 10; ++i) {
        float r = 0.f;
        #pragma unroll
        for (int j = 0; j < 10; ++j) r += acc[i][j];
        r += __shfl_xor(r, 1, 64); r += __shfl_xor(r, 2, 64);
        r += __shfl_xor(r, 4, 64); r += __shfl_xor(r, 8, 64);
        if (tx == 0) A1[ty + 16 * i] = r;       // unique writer per s
    }
    // ---- col sums -> A2 (2 in-wave ty via shfl, 4 waves via LDS atomic) ----
    #pragma unroll
    for (int j = 0; j < 10; ++j) {
        float cs = 0.f;
        #pragma unroll
        for (int i = 0; i < 10; ++i) cs += acc[i][j];
        cs += __shfl_xor(cs, 16, 64);
        cs += __shfl_xor(cs, 32, 64);
        if (lane < 16) atomicAdd(&A2[tx + 16 * j], cs);
    }
    __syncthreads();

    const float l = (wred[4] + wred[5]) + (wred[6] + wred[7]);
    if (tid == 0)
        out[(size_t)NB * NH * SS * DD + (size_t)bh * SS + qi] = m + __logf(l);

    // ---- z[q,d] = (A1 @ v1 + A2 @ v2) / l ----
    const int d    = tid & 63;
    const int part = tid >> 6;                  // 0..3, 40 rows each
    const float* v1p = v1 + base;
    const float* v2p = v2 + base;
    float z = 0.f;
    #pragma unroll 4
    for (int s = part * 40; s < part * 40 + 40; ++s)
        z = fmaf(A1[s], v1p[s * DD + d], fmaf(A2[s], v2p[s * DD + d], z));
    zred[tid] = z;
    __syncthreads();
    if (tid < DD) {
        float zz = (zred[tid] + zred[tid + 64]) + (zred[tid + 128] + zred[tid + 192]);
        out[((size_t)bh * SS + qi) * DD + tid] = zz / l;
    }
}

extern "C" void kernel_launch(void* const* d_in, const int* in_sizes, int n_in,
                              void* d_out, int out_size, void* d_ws, size_t ws_size,
                              hipStream_t stream) {
    const float* q  = (const float*)d_in[0];
    const float* k1 = (const float*)d_in[1];
    const float* k2 = (const float*)d_in[2];
    const float* v1 = (const float*)d_in[3];
    const float* v2 = (const float*)d_in[4];
    float* out = (float*)d_out;
    tritt_kernel<<<dim3(NB * NH * SS), dim3(NT), 0, stream>>>(q, k1, k2, v1, v2, out);
}

// Round 3
// 126.775 us; speedup vs baseline: 1.5325x; 1.4574x over previous
//
#include <hip/hip_runtime.h>
#include <math.h>

#define NB 2
#define NH 8
#define SS 160
#define DD 64
#define NT 256

typedef __attribute__((ext_vector_type(8))) short bf16x8;
typedef __attribute__((ext_vector_type(4))) float f32x4;

// split a pair of fp32 into packed bf16 (hi, lo) with truncation; lo captures
// the residual exactly-ish (total rep error ~2^-16 relative).
__device__ __forceinline__ uint2 splitpair(float a0, float a1) {
    unsigned u0 = __float_as_uint(a0), u1 = __float_as_uint(a1);
    unsigned hi = (u0 >> 16) | (u1 & 0xffff0000u);
    float r0 = a0 - __uint_as_float(u0 & 0xffff0000u);
    float r1 = a1 - __uint_as_float(u1 & 0xffff0000u);
    unsigned v0 = __float_as_uint(r0), v1 = __float_as_uint(r1);
    unsigned lo = (v0 >> 16) | (v1 & 0xffff0000u);
    return make_uint2(hi, lo);
}

// LDS: 4 arrays of [160 rows][8 groups of 8 bf16] = 20480 B each:
//   A_hi @0, A_lo @20480, B_hi @40960, B_lo @61440.  Group g of row s is
//   stored at group slot g^(s&7): fragment reads and staging writes are both
//   <=2-way bank conflicted (free), and all tile offsets become immediates.
__global__ __launch_bounds__(NT, 2) void tritt_kernel(
    const float* __restrict__ q,  const float* __restrict__ k1,
    const float* __restrict__ k2, const float* __restrict__ v1,
    const float* __restrict__ v2, float* __restrict__ out)
{
    __shared__ __align__(16) char sm[81920];

    const int tid = threadIdx.x;
    const int blk = blockIdx.x;
    const int bh  = blk / SS;
    const int qi  = blk % SS;
    const size_t base = (size_t)bh * SS * DD;

    const float4* k1f = (const float4*)(k1 + base);
    const float4* k2f = (const float4*)(k2 + base);
    const float4* qf  = (const float4*)(q + base + (size_t)qi * DD);

    // ---- stage: A = q ⊙ k1 and B = k2, split to bf16 hi/lo in LDS ----
    #pragma unroll
    for (int it = 0; it < 5; ++it) {
        int f = tid + NT * it;            // 0..1279 = 160 rows x 8 groups
        int s = f >> 3, g = f & 7;
        int fg = s * 16 + g * 2;          // float4 index of 8-float group
        float4 x0 = k1f[fg], x1 = k1f[fg + 1];
        float4 y0 = k2f[fg], y1 = k2f[fg + 1];
        float4 q0 = qf[g * 2], q1 = qf[g * 2 + 1];

        uint2 pa0 = splitpair(x0.x * q0.x, x0.y * q0.y);
        uint2 pa1 = splitpair(x0.z * q0.z, x0.w * q0.w);
        uint2 pa2 = splitpair(x1.x * q1.x, x1.y * q1.y);
        uint2 pa3 = splitpair(x1.z * q1.z, x1.w * q1.w);
        uint2 pb0 = splitpair(y0.x, y0.y);
        uint2 pb1 = splitpair(y0.z, y0.w);
        uint2 pb2 = splitpair(y1.x, y1.y);
        uint2 pb3 = splitpair(y1.z, y1.w);

        uint4 ahi = make_uint4(pa0.x, pa1.x, pa2.x, pa3.x);
        uint4 alo = make_uint4(pa0.y, pa1.y, pa2.y, pa3.y);
        uint4 bhi = make_uint4(pb0.x, pb1.x, pb2.x, pb3.x);
        uint4 blo = make_uint4(pb0.y, pb1.y, pb2.y, pb3.y);

        int off = s * 128 + ((g ^ (s & 7)) * 16);
        *(uint4*)(sm + off)         = ahi;
        *(uint4*)(sm + 20480 + off) = alo;
        *(uint4*)(sm + 40960 + off) = bhi;
        *(uint4*)(sm + 61440 + off) = blo;
    }
    __syncthreads();

    // ---- MFMA K-loop: wave (wy,wx) owns s in [80wy,+80), t in [80wx,+80) ----
    const int lane = tid & 63;
    const int wid  = tid >> 6;
    const int wy = wid >> 1, wx = wid & 1;
    const int s0 = 80 * wy, t0 = 80 * wx;
    const int n16 = lane & 15, quad = lane >> 4, l7 = lane & 7;

    f32x4 acc[5][5];
    #pragma unroll
    for (int i = 0; i < 5; ++i)
        #pragma unroll
        for (int j = 0; j < 5; ++j) acc[i][j] = (f32x4){0.f, 0.f, 0.f, 0.f};

    #pragma unroll 1
    for (int ks = 0; ks < 2; ++ks) {
        const int sg = (4 * ks + quad) ^ l7;   // swizzled group, uniform per lane
        const char* abase = sm + (s0 + n16) * 128 + sg * 16;
        const char* bbase = sm + 40960 + (t0 + n16) * 128 + sg * 16;
        bf16x8 ah[5], al[5];
        #pragma unroll
        for (int i = 0; i < 5; ++i) {
            ah[i] = *(const bf16x8*)(abase + 2048 * i);
            al[i] = *(const bf16x8*)(abase + 20480 + 2048 * i);
        }
        #pragma unroll
        for (int j = 0; j < 5; ++j) {
            bf16x8 bh8 = *(const bf16x8*)(bbase + 2048 * j);
            bf16x8 bl8 = *(const bf16x8*)(bbase + 20480 + 2048 * j);
            #pragma unroll
            for (int i = 0; i < 5; ++i) {
                acc[i][j] = __builtin_amdgcn_mfma_f32_16x16x32_bf16(ah[i], bh8, acc[i][j], 0, 0, 0);
                acc[i][j] = __builtin_amdgcn_mfma_f32_16x16x32_bf16(al[i], bh8, acc[i][j], 0, 0, 0);
                acc[i][j] = __builtin_amdgcn_mfma_f32_16x16x32_bf16(ah[i], bl8, acc[i][j], 0, 0, 0);
            }
        }
    }
    __syncthreads();   // staging LDS dead; alias reduction arrays

    float* A1   = (float*)sm;           // [160] row sums (over t)
    float* A2   = A1 + SS;              // [160] col sums (over s)
    float* wred = A2 + SS;              // [8]
    float* zred = wred + 8;             // [256]

    if (tid < SS) { A1[tid] = 0.f; A2[tid] = 0.f; }

    // ---- block max ----
    float mloc = -1e30f;
    #pragma unroll
    for (int i = 0; i < 5; ++i)
        #pragma unroll
        for (int j = 0; j < 5; ++j)
            #pragma unroll
            for (int r = 0; r < 4; ++r) mloc = fmaxf(mloc, acc[i][j][r]);
    #pragma unroll
    for (int off = 32; off; off >>= 1) mloc = fmaxf(mloc, __shfl_xor(mloc, off, 64));
    if (lane == 0) wred[wid] = mloc;
    __syncthreads();
    const float m = fmaxf(fmaxf(wred[0], wred[1]), fmaxf(wred[2], wred[3]));

    // ---- exp in place + block sum ----
    float lsum = 0.f;
    #pragma unroll
    for (int i = 0; i < 5; ++i)
        #pragma unroll
        for (int j = 0; j < 5; ++j)
            #pragma unroll
            for (int r = 0; r < 4; ++r) {
                float e = __expf(acc[i][j][r] - m);
                acc[i][j][r] = e;
                lsum += e;
            }
    #pragma unroll
    for (int off = 32; off; off >>= 1) lsum += __shfl_xor(lsum, off, 64);
    if (lane == 0) wred[4 + wid] = lsum;

    // ---- row sums: s = s0 + 16i + 4*quad + r; reduce over n (low 4 lane bits) ----
    #pragma unroll
    for (int i = 0; i < 5; ++i)
        #pragma unroll
        for (int r = 0; r < 4; ++r) {
            float rs = 0.f;
            #pragma unroll
            for (int j = 0; j < 5; ++j) rs += acc[i][j][r];
            rs += __shfl_xor(rs, 1, 64); rs += __shfl_xor(rs, 2, 64);
            rs += __shfl_xor(rs, 4, 64); rs += __shfl_xor(rs, 8, 64);
            if (n16 == 0) atomicAdd(&A1[s0 + 16 * i + 4 * quad + r], rs);
        }
    // ---- col sums: t = t0 + 16j + n; reduce over quad (lane bits 4,5) ----
    #pragma unroll
    for (int j = 0; j < 5; ++j) {
        float cs = 0.f;
        #pragma unroll
        for (int i = 0; i < 5; ++i)
            #pragma unroll
            for (int r = 0; r < 4; ++r) cs += acc[i][j][r];
        cs += __shfl_xor(cs, 16, 64);
        cs += __shfl_xor(cs, 32, 64);
        if (quad == 0) atomicAdd(&A2[t0 + 16 * j + n16], cs);
    }
    __syncthreads();

    const float l = (wred[4] + wred[5]) + (wred[6] + wred[7]);
    if (tid == 0)
        out[(size_t)NB * NH * SS * DD + (size_t)bh * SS + qi] = m + __logf(l);

    // ---- z[q,d] = (A1 @ v1 + A2 @ v2) / l ----
    const int d    = tid & 63;
    const int part = tid >> 6;
    const float* v1p = v1 + base;
    const float* v2p = v2 + base;
    float z = 0.f;
    #pragma unroll 4
    for (int s = part * 40; s < part * 40 + 40; ++s)
        z = fmaf(A1[s], v1p[s * DD + d], fmaf(A2[s], v2p[s * DD + d], z));
    zred[tid] = z;
    __syncthreads();
    if (tid < DD) {
        float zz = (zred[tid] + zred[tid + 64]) + (zred[tid + 128] + zred[tid + 192]);
        out[((size_t)bh * SS + qi) * DD + tid] = zz / l;
    }
}

extern "C" void kernel_launch(void* const* d_in, const int* in_sizes, int n_in,
                              void* d_out, int out_size, void* d_ws, size_t ws_size,
                              hipStream_t stream) {
    const float* q  = (const float*)d_in[0];
    const float* k1 = (const float*)d_in[1];
    const float* k2 = (const float*)d_in[2];
    const float* v1 = (const float*)d_in[3];
    const float* v2 = (const float*)d_in[4];
    float* out = (float*)d_out;
    tritt_kernel<<<dim3(NB * NH * SS), dim3(NT), 0, stream>>>(q, k1, k2, v1, v2, out);
}